// Round 3
// baseline (43.488 us; speedup 1.0000x reference)
//
#include <hip/hip_runtime.h>

#define NST 10
#define NLBL 50
#define BATCH 256
#define TLEN 1024
#define TPB 512
#define HALO 8
#define ROWS (TPB + 2*HALO)   // 528
#define EPAD 13
#define PRPAD 13
#define SC 1.0e15f
#define LN2F 0.69314718055994531f

__global__ __launch_bounds__(256, 2) void k_all(const int* __restrict__ sent,
                                                const float* __restrict__ W,
                                                const float* __restrict__ trans,
                                                const float* __restrict__ outw,
                                                float* __restrict__ out) {
    __shared__ alignas(16) float Elds[ROWS][EPAD];   // 27.5 KB
    __shared__ alignas(16) float prl[TPB][PRPAD];    // 26.6 KB
    __shared__ alignas(16) float Tl[112];
    __shared__ alignas(16) float Ttl[112];
    __shared__ alignas(16) float Ol[NST][56];

    const int tid = threadIdx.x;
    const int b   = (int)blockIdx.x >> 1;
    const int tb  = ((int)blockIdx.x & 1) * TPB;

    // ---- parameter prep (redundant per block; cheap) ----
    if (tid < NST) {
        float r[NST]; float m = -1e30f, s = 0.f;
        #pragma unroll
        for (int j = 0; j < NST; ++j) { r[j] = trans[tid*NST + j]; m = fmaxf(m, r[j]); }
        #pragma unroll
        for (int j = 0; j < NST; ++j) { r[j] = __expf(r[j] - m); s += r[j]; }
        float inv = 1.f / s;
        #pragma unroll
        for (int j = 0; j < NST; ++j) { Tl[tid*NST + j] = r[j]*inv; Ttl[j*NST + tid] = r[j]*inv; }
    } else if (tid >= 32 && tid < 32 + NST) {
        const int i = tid - 32;
        float m = -1e30f, s = 0.f; float r[NLBL];
        for (int l = 0; l < NLBL; ++l) { r[l] = outw[i*NLBL + l]; m = fmaxf(m, r[l]); }
        for (int l = 0; l < NLBL; ++l) { r[l] = __expf(r[l] - m); s += r[l]; }
        float inv = 1.f / s;
        for (int l = 0; l < NLBL; ++l) Ol[i][l] = r[l]*inv;
        for (int l = NLBL; l < 56; ++l) Ol[i][l] = 0.f;
    }

    // ---- emission staging: gather W[tok], softmax, -> LDS ----
    const int* sb = sent + b*TLEN;
    for (int r = tid; r < ROWS; r += 256) {
        int p  = tb - HALO + r;
        int pc = min(max(p, 0), TLEN-1);
        int tok = sb[pc];
        const float2* w2 = reinterpret_cast<const float2*>(W + (size_t)tok*NST);
        float2 q0=w2[0], q1=w2[1], q2=w2[2], q3=w2[3], q4=w2[4];
        float e[10] = {q0.x,q0.y,q1.x,q1.y,q2.x,q2.y,q3.x,q3.y,q4.x,q4.y};
        float m = e[0];
        #pragma unroll
        for (int j=1;j<10;++j) m = fmaxf(m, e[j]);
        float s = 0.f;
        #pragma unroll
        for (int j=0;j<10;++j) { e[j] = __expf(e[j]-m); s += e[j]; }
        float inv = 1.f/s;
        #pragma unroll
        for (int j=0;j<10;++j) Elds[r][j] = e[j]*inv;
    }
    __syncthreads();

    const int t0  = tb + 2*tid;     // this thread's chunk = {t0, t0+1}
    const int lr0 = 2*tid;          // LDS row of global position t0-HALO

    float vT[100];
    #pragma unroll
    for (int k=0;k<100;++k) vT[k] = Tl[k];

    // ---- forward: 9 steps from t0-HALO, keep alpha(t0), alpha(t0+1) ----
    float alpha[10], a0s[10], a1s[10];
    #pragma unroll
    for (int s=0;s<10;++s) alpha[s] = Elds[lr0][s] * SC;

    #pragma unroll
    for (int i=1;i<=HALO+1;++i) {
        const int p = t0 - HALO + i;
        float an[10];
        #pragma unroll
        for (int s=0;s<10;++s) {
            float acc = 0.f;
            #pragma unroll
            for (int j=0;j<10;++j) acc = fmaf(vT[s*10+j], alpha[j], acc);
            an[s] = acc * Elds[lr0+i][s];
        }
        const bool upd = (p >= 1);
        #pragma unroll
        for (int s=0;s<10;++s) alpha[s] = upd ? an[s] : alpha[s];
        if (i == HALO) {
            #pragma unroll
            for (int s=0;s<10;++s) a0s[s] = alpha[s];
        }
    }
    #pragma unroll
    for (int s=0;s<10;++s) a1s[s] = alpha[s];

    // ---- backward: 9 steps from t0+HALO+1 down to t0; fuse posterior ----
    #pragma unroll
    for (int k=0;k<100;++k) vT[k] = Ttl[k];   // now holds T^T

    float g[10];
    const int lre = 2*tid + 2*HALO + 1;       // LDS row of t0+HALO+1 (clamped data)
    #pragma unroll
    for (int s=0;s<10;++s) g[s] = Elds[lre][s] * SC;

    #pragma unroll
    for (int i=1;i<=HALO+1;++i) {
        const int p = t0 + HALO + 1 - i;
        float u[10];
        #pragma unroll
        for (int s=0;s<10;++s) {
            float acc = 0.f;
            #pragma unroll
            for (int j=0;j<10;++j) acc = fmaf(vT[s*10+j], g[j], acc);
            u[s] = acc;
        }
        const bool last = (p == TLEN-1);
        #pragma unroll
        for (int s=0;s<10;++s) u[s] = last ? SC : u[s];
        if (i == HALO) {          // p == t0+1
            float sum = 0.f; float pr[10];
            #pragma unroll
            for (int s=0;s<10;++s) { pr[s] = a1s[s]*u[s]; sum += pr[s]; }
            #pragma unroll
            for (int s=0;s<10;++s) prl[2*tid+1][s] = pr[s];
            prl[2*tid+1][10] = __log2f(sum);
        }
        if (i == HALO+1) {        // p == t0
            float sum = 0.f; float pr[10];
            #pragma unroll
            for (int s=0;s<10;++s) { pr[s] = a0s[s]*u[s]; sum += pr[s]; }
            #pragma unroll
            for (int s=0;s<10;++s) prl[2*tid][s] = pr[s];
            prl[2*tid][10] = __log2f(sum);
        }
        const bool keep = (p > TLEN-1);
        #pragma unroll
        for (int s=0;s<10;++s) {
            float gn = Elds[lre - i][s] * u[s];
            g[s] = keep ? g[s] : gn;
        }
    }
    __syncthreads();

    // ---- combine: out[t][l] = (log2(dot(pr, O[:,l])) - log2(sum pr)) * ln2 ----
    const int lg = tid & 7;
    const int tq = tid >> 3;
    const int lb = lg * 7;                    // labels lb..lb+6 (masked at 50)
    float vO[10][7];
    #pragma unroll
    for (int s=0;s<10;++s)
        #pragma unroll
        for (int k=0;k<7;++k) vO[s][k] = Ol[s][lb+k];

    float* ob = out + ((size_t)b*TLEN + tb)*NLBL;
    for (int it=0; it<16; ++it) {
        const int t = tq + 32*it;
        float pv[10];
        #pragma unroll
        for (int s=0;s<10;++s) pv[s] = prl[t][s];
        const float ls = prl[t][10];
        float* orow = ob + t*NLBL + lb;
        #pragma unroll
        for (int k=0;k<7;++k) {
            float d = 0.f;
            #pragma unroll
            for (int s=0;s<10;++s) d = fmaf(pv[s], vO[s][k], d);
            float v = (__log2f(d) - ls) * LN2F;
            if (lb + k < NLBL) orow[k] = v;
        }
    }
}

extern "C" void kernel_launch(void* const* d_in, const int* in_sizes, int n_in,
                              void* d_out, int out_size, void* d_ws, size_t ws_size,
                              hipStream_t stream) {
    const int*   sent  = (const int*)d_in[0];
    const float* W     = (const float*)d_in[1];
    const float* trans = (const float*)d_in[2];
    const float* outw  = (const float*)d_in[3];
    float* out = (float*)d_out;

    hipLaunchKernelGGL(k_all, dim3(BATCH * (TLEN / TPB)), dim3(256), 0, stream,
                       sent, W, trans, outw, out);
}

// Round 4
// 43.456 us; speedup vs baseline: 1.0007x; 1.0007x over previous
//
#include <hip/hip_runtime.h>

#define NST 10
#define NLBL 50
#define BATCH 256
#define TLEN 1024
#define TPB 512
#define HALO 8
#define ROWS (TPB + 2*HALO)   // 528
#define EPAD 13
#define PRPAD 13
#define SC 1.0e15f
#define LN2F 0.69314718055994531f

__global__ __launch_bounds__(256, 2) void k_all(const int* __restrict__ sent,
                                                const float* __restrict__ W,
                                                const float* __restrict__ trans,
                                                const float* __restrict__ outw,
                                                float* __restrict__ out) {
    __shared__ alignas(16) float Elds[ROWS][EPAD];   // 27.5 KB
    __shared__ alignas(16) float prl[TPB][PRPAD];    // 26.6 KB
    __shared__ alignas(16) float Tl[112];
    __shared__ alignas(16) float Ttl[112];
    __shared__ alignas(16) float Ol[NST][56];

    const int tid = threadIdx.x;
    const int b   = (int)blockIdx.x >> 1;
    const int tb  = ((int)blockIdx.x & 1) * TPB;

    // ---- parameter prep (redundant per block; cheap) ----
    if (tid < NST) {
        float r[NST]; float m = -1e30f, s = 0.f;
        #pragma unroll
        for (int j = 0; j < NST; ++j) { r[j] = trans[tid*NST + j]; m = fmaxf(m, r[j]); }
        #pragma unroll
        for (int j = 0; j < NST; ++j) { r[j] = __expf(r[j] - m); s += r[j]; }
        float inv = 1.f / s;
        #pragma unroll
        for (int j = 0; j < NST; ++j) { Tl[tid*NST + j] = r[j]*inv; Ttl[j*NST + tid] = r[j]*inv; }
    } else if (tid >= 32 && tid < 32 + NST) {
        const int i = tid - 32;
        float m = -1e30f, s = 0.f; float r[NLBL];
        for (int l = 0; l < NLBL; ++l) { r[l] = outw[i*NLBL + l]; m = fmaxf(m, r[l]); }
        for (int l = 0; l < NLBL; ++l) { r[l] = __expf(r[l] - m); s += r[l]; }
        float inv = 1.f / s;
        for (int l = 0; l < NLBL; ++l) Ol[i][l] = r[l]*inv;
        for (int l = NLBL; l < 56; ++l) Ol[i][l] = 0.f;
    }

    // ---- emission staging: gather W[tok], softmax, -> LDS ----
    const int* sb = sent + b*TLEN;
    for (int r = tid; r < ROWS; r += 256) {
        int p  = tb - HALO + r;
        int pc = min(max(p, 0), TLEN-1);
        int tok = sb[pc];
        const float2* w2 = reinterpret_cast<const float2*>(W + (size_t)tok*NST);
        float2 q0=w2[0], q1=w2[1], q2=w2[2], q3=w2[3], q4=w2[4];
        float e[10] = {q0.x,q0.y,q1.x,q1.y,q2.x,q2.y,q3.x,q3.y,q4.x,q4.y};
        float m = e[0];
        #pragma unroll
        for (int j=1;j<10;++j) m = fmaxf(m, e[j]);
        float s = 0.f;
        #pragma unroll
        for (int j=0;j<10;++j) { e[j] = __expf(e[j]-m); s += e[j]; }
        float inv = 1.f/s;
        #pragma unroll
        for (int j=0;j<10;++j) Elds[r][j] = e[j]*inv;
    }
    __syncthreads();

    const int t0  = tb + 2*tid;     // this thread's chunk = {t0, t0+1}
    const int lr0 = 2*tid;          // LDS row of global position t0-HALO

    float vT[100];
    #pragma unroll
    for (int k=0;k<100;++k) vT[k] = Tl[k];

    // ---- forward: 9 steps from t0-HALO, keep alpha(t0), alpha(t0+1) ----
    float alpha[10], a0s[10], a1s[10];
    #pragma unroll
    for (int s=0;s<10;++s) alpha[s] = Elds[lr0][s] * SC;

    #pragma unroll
    for (int i=1;i<=HALO+1;++i) {
        const int p = t0 - HALO + i;
        float an[10];
        #pragma unroll
        for (int s=0;s<10;++s) {
            float acc = 0.f;
            #pragma unroll
            for (int j=0;j<10;++j) acc = fmaf(vT[s*10+j], alpha[j], acc);
            an[s] = acc * Elds[lr0+i][s];
        }
        const bool upd = (p >= 1);
        #pragma unroll
        for (int s=0;s<10;++s) alpha[s] = upd ? an[s] : alpha[s];
        if (i == HALO) {
            #pragma unroll
            for (int s=0;s<10;++s) a0s[s] = alpha[s];
        }
    }
    #pragma unroll
    for (int s=0;s<10;++s) a1s[s] = alpha[s];

    // ---- backward: 9 steps from t0+HALO+1 down to t0; fuse posterior ----
    #pragma unroll
    for (int k=0;k<100;++k) vT[k] = Ttl[k];   // now holds T^T

    float g[10];
    const int lre = 2*tid + 2*HALO + 1;       // LDS row of t0+HALO+1 (clamped data)
    #pragma unroll
    for (int s=0;s<10;++s) g[s] = Elds[lre][s] * SC;

    #pragma unroll
    for (int i=1;i<=HALO+1;++i) {
        const int p = t0 + HALO + 1 - i;
        float u[10];
        #pragma unroll
        for (int s=0;s<10;++s) {
            float acc = 0.f;
            #pragma unroll
            for (int j=0;j<10;++j) acc = fmaf(vT[s*10+j], g[j], acc);
            u[s] = acc;
        }
        const bool last = (p == TLEN-1);
        #pragma unroll
        for (int s=0;s<10;++s) u[s] = last ? SC : u[s];
        if (i == HALO) {          // p == t0+1
            float sum = 0.f; float pr[10];
            #pragma unroll
            for (int s=0;s<10;++s) { pr[s] = a1s[s]*u[s]; sum += pr[s]; }
            #pragma unroll
            for (int s=0;s<10;++s) prl[2*tid+1][s] = pr[s];
            prl[2*tid+1][10] = __log2f(sum);
        }
        if (i == HALO+1) {        // p == t0
            float sum = 0.f; float pr[10];
            #pragma unroll
            for (int s=0;s<10;++s) { pr[s] = a0s[s]*u[s]; sum += pr[s]; }
            #pragma unroll
            for (int s=0;s<10;++s) prl[2*tid][s] = pr[s];
            prl[2*tid][10] = __log2f(sum);
        }
        const bool keep = (p > TLEN-1);
        #pragma unroll
        for (int s=0;s<10;++s) {
            float gn = Elds[lre - i][s] * u[s];
            g[s] = keep ? g[s] : gn;
        }
    }
    __syncthreads();

    // ---- combine: out[t][l] = (log2(dot(pr, O[:,l])) - log2(sum pr)) * ln2 ----
    const int lg = tid & 7;
    const int tq = tid >> 3;
    const int lb = lg * 7;                    // labels lb..lb+6 (masked at 50)
    float vO[10][7];
    #pragma unroll
    for (int s=0;s<10;++s)
        #pragma unroll
        for (int k=0;k<7;++k) vO[s][k] = Ol[s][lb+k];

    float* ob = out + ((size_t)b*TLEN + tb)*NLBL;
    for (int it=0; it<16; ++it) {
        const int t = tq + 32*it;
        float pv[10];
        #pragma unroll
        for (int s=0;s<10;++s) pv[s] = prl[t][s];
        const float ls = prl[t][10];
        float* orow = ob + t*NLBL + lb;
        #pragma unroll
        for (int k=0;k<7;++k) {
            float d = 0.f;
            #pragma unroll
            for (int s=0;s<10;++s) d = fmaf(pv[s], vO[s][k], d);
            float v = (__log2f(d) - ls) * LN2F;
            if (lb + k < NLBL) orow[k] = v;
        }
    }
}

extern "C" void kernel_launch(void* const* d_in, const int* in_sizes, int n_in,
                              void* d_out, int out_size, void* d_ws, size_t ws_size,
                              hipStream_t stream) {
    const int*   sent  = (const int*)d_in[0];
    const float* W     = (const float*)d_in[1];
    const float* trans = (const float*)d_in[2];
    const float* outw  = (const float*)d_in[3];
    float* out = (float*)d_out;

    hipLaunchKernelGGL(k_all, dim3(BATCH * (TLEN / TPB)), dim3(256), 0, stream,
                       sent, W, trans, outw, out);
}